// Round 6
// baseline (288.131 us; speedup 1.0000x reference)
//
#include <hip/hip_runtime.h>
#include <cstdint>
#include <cstddef>

#define B_SZ   8
#define SEQ    4096
#define HID    1024
#define NCH    4         // snn time chunks
#define CHUNK  1024      // SEQ / NCH
#define WARM   256       // warm-up steps; bit-exact (validated rounds 4-5)
#define JTAP   16        // truncated SSM impulse-response taps
#define TS     32        // yout t-tile
#define TT     32        // snn LDS time-tile
#define HB     128       // snn hid-slab per block

typedef float vfloat4 __attribute__((ext_vector_type(4)));

// ws layout: u64 spk[B_SZ*16*SEQ] = 4 MB at offset 0
__device__ __forceinline__ void snn_step(float& v, float& r, float xv, bool& s) {
  // match reference rounding: separate mul + add (no FMA contraction)
  v = __fadd_rn(__fmul_rn(v, 0.9f), xv);
  s = (r <= 0.0f) && (v >= 1.0f);
  v = s ? 0.0f : v;
  r = s ? 5.0f : fmaxf(r - 1.0f, 0.0f);
}

// async global->LDS DMA, 16B/lane (wave-uniform LDS base + lane*16)
__device__ __forceinline__ void async_ld16(const float* g, float* l) {
  __builtin_amdgcn_global_load_lds((const __attribute__((address_space(1))) void*)g,
                                   (__attribute__((address_space(3))) void*)l,
                                   16, 0, 0);
}

// Phase 1: LIF scan. grid = (8, B_SZ, NCH) = 256 blocks of 128 threads.
// x streamed via async DMA into double-buffered LDS tiles (32t x 128hid);
// the serial chain reads LDS (conflict-free), so global latency is hidden by
// the tile pipeline instead of per-thread register batches (which the
// compiler previously sank, VGPR=20 evidence).
__global__ __launch_bounds__(128) void snn_kernel(const float* __restrict__ x,
                                                  unsigned long long* __restrict__ spk) {
  __shared__ float tile[2][TT][HB];        // 2 x 16 KB
  const int tid  = threadIdx.x;            // 0..127
  const int lane = tid & 63;
  const int w    = tid >> 6;               // wave 0/1
  const int hb   = blockIdx.x;             // hid slab 0..7
  const int b    = blockIdx.y;
  const int c    = blockIdx.z;             // chunk 0..3
  const int t0   = c * CHUNK;
  const int tw   = (c == 0) ? 0 : (t0 - WARM);
  const int nt   = (t0 + CHUNK - tw) / TT; // 32 or 40 tiles
  const float* __restrict__ gbase = x + (size_t)(b * SEQ) * HID + hb * HB;
  const int wv = hb * 2 + w;               // global hid-wave index 0..15
  unsigned long long* __restrict__ sp = spk + (size_t)(b * 16 + wv) * SEQ;

  // per-lane offset within a 1KB (2-row) DMA segment: lanes 0-31 row+0, 32-63 row+1
  const size_t goff = (size_t)(lane >> 5) * HID + (size_t)(lane & 31) * 4;

  // prefetch tile 0
  {
    const float* g0 = gbase + (size_t)tw * HID + goff;
    float* l0 = &tile[0][0][0];
    #pragma unroll
    for (int p = 0; p < 8; ++p)
      async_ld16(g0 + (size_t)(w * 16 + 2 * p) * HID, l0 + (w * 8 + p) * 256);
  }

  float v = 0.0f, r = 0.0f;
  for (int i = 0; i < nt; ++i) {
    __syncthreads();                       // drains DMA: tile i resident
    const int tt = tw + i * TT;

    if (i + 1 < nt) {                      // prefetch tile i+1 (flies during process)
      const float* g = gbase + (size_t)(tt + TT) * HID + goff;
      float* l = &tile[(i + 1) & 1][0][0];
      #pragma unroll
      for (int p = 0; p < 8; ++p)
        async_ld16(g + (size_t)(w * 16 + 2 * p) * HID, l + (w * 8 + p) * 256);
    }

    const float (*tl)[HB] = tile[i & 1];
    if (tt >= t0) {                        // emit tile (wave-uniform branch)
      unsigned long long my = 0;
      #pragma unroll
      for (int g8 = 0; g8 < 4; ++g8) {
        float xv[8];
        #pragma unroll
        for (int k = 0; k < 8; ++k) xv[k] = tl[g8 * 8 + k][tid];
        #pragma unroll
        for (int k = 0; k < 8; ++k) {
          bool s; snn_step(v, r, xv[k], s);
          unsigned long long m = __ballot(s);
          my = ((lane & 31) == (g8 * 8 + k)) ? m : my;
        }
      }
      if (lane < 32) sp[tt + lane] = my;   // 256B coalesced burst per tile
    } else {                               // warm-up tile
      #pragma unroll
      for (int g8 = 0; g8 < 4; ++g8) {
        float xv[8];
        #pragma unroll
        for (int k = 0; k < 8; ++k) xv[k] = tl[g8 * 8 + k][tid];
        #pragma unroll
        for (int k = 0; k < 8; ++k) { bool s; snn_step(v, r, xv[k], s); }
      }
    }
  }
}

// Phase 2 (fused): grid = (SEQ/TS, B_SZ) = 1024 blocks (4/CU).
// wave0 computes w_m = C.A^m.B (overlapped with staging by waves 1-3);
// u popcounts, 16-tap conv, nontemporal stream-out.
__global__ __launch_bounds__(256) void yout_kernel(const unsigned long long* __restrict__ spk,
                                                   const float* __restrict__ A,
                                                   const float* __restrict__ Bv,
                                                   const float* __restrict__ Cv,
                                                   const float* __restrict__ Dp,
                                                   vfloat4* __restrict__ out) {
  __shared__ unsigned long long lm[16][TS + JTAP];
  __shared__ float ws[JTAP];
  __shared__ float su[TS + JTAP];
  __shared__ float sy[TS];

  const int tid = threadIdx.x;
  const int b   = blockIdx.y;
  const int t0  = blockIdx.x * TS;
  const unsigned long long* __restrict__ sb = spk + (size_t)b * 16 * SEQ;

  if (tid < 64) {
    const int lane = tid;
    float arow[64];
    #pragma unroll 8
    for (int s2 = 0; s2 < 64; ++s2) arow[s2] = A[lane * 64 + s2];
    float p = Bv[lane];
    const float cv = Cv[lane];
    for (int m = 0; m < JTAP; ++m) {
      float t = cv * p;
      #pragma unroll
      for (int off = 32; off; off >>= 1) t += __shfl_xor(t, off);
      if (lane == 0) ws[m] = t;
      float n0 = 0.f, n1 = 0.f, n2 = 0.f, n3 = 0.f;
      #pragma unroll
      for (int s2 = 0; s2 < 64; s2 += 4) {
        n0 = fmaf(arow[s2 + 0], __shfl(p, s2 + 0), n0);
        n1 = fmaf(arow[s2 + 1], __shfl(p, s2 + 1), n1);
        n2 = fmaf(arow[s2 + 2], __shfl(p, s2 + 2), n2);
        n3 = fmaf(arow[s2 + 3], __shfl(p, s2 + 3), n3);
      }
      p = (n0 + n1) + (n2 + n3);
    }
  } else {
    const int i = tid - 64;
    if (i < TS + JTAP) {
      const int t = t0 - JTAP + i;
      #pragma unroll
      for (int wv = 0; wv < 16; ++wv)
        lm[wv][i] = (t >= 0) ? sb[(size_t)wv * SEQ + t] : 0ull;
    }
  }
  __syncthreads();

  if (tid < TS + JTAP) {
    int cc = 0;
    #pragma unroll
    for (int wv = 0; wv < 16; ++wv) cc += __popcll(lm[wv][tid]);
    su[tid] = cc * (1.0f / 1024.0f);
  }
  __syncthreads();

  if (tid < TS) {
    float acc = Dp[0] * su[JTAP + tid];
    #pragma unroll
    for (int m = 0; m < JTAP; ++m) acc = fmaf(ws[m], su[JTAP + tid - m], acc);
    sy[tid] = acc;
  }
  __syncthreads();

  const int wv = tid >> 4;
  const int sh = (tid & 15) * 4;
  vfloat4* op = out + (size_t)(b * SEQ + t0) * 256 + tid;
  #pragma unroll 8
  for (int j = 0; j < TS; ++j) {
    const unsigned long long m = lm[wv][JTAP + j];
    const float yv = sy[j];
    vfloat4 o;
    o.x = ((m >> (sh + 0)) & 1ull) ? 1.0f + yv : yv;
    o.y = ((m >> (sh + 1)) & 1ull) ? 1.0f + yv : yv;
    o.z = ((m >> (sh + 2)) & 1ull) ? 1.0f + yv : yv;
    o.w = ((m >> (sh + 3)) & 1ull) ? 1.0f + yv : yv;
    __builtin_nontemporal_store(o, &op[(size_t)j * 256]);
  }
}

extern "C" void kernel_launch(void* const* d_in, const int* in_sizes, int n_in,
                              void* d_out, int out_size, void* d_ws, size_t ws_size,
                              hipStream_t stream) {
  const float* x  = (const float*)d_in[0];   // (8, 4096, 1024)
  const float* A  = (const float*)d_in[1];   // (64, 64)
  const float* Bv = (const float*)d_in[2];   // (64, 1)
  const float* Cv = (const float*)d_in[3];   // (1, 64)
  const float* Dp = (const float*)d_in[4];   // (1, 1)

  unsigned long long* spk = (unsigned long long*)d_ws;   // 4 MB

  dim3 g1(HID / HB, B_SZ, NCH);
  snn_kernel<<<g1, 128, 0, stream>>>(x, spk);

  dim3 g2(SEQ / TS, B_SZ);
  yout_kernel<<<g2, 256, 0, stream>>>(spk, A, Bv, Cv, Dp, (vfloat4*)d_out);
}

// Round 7
// 286.848 us; speedup vs baseline: 1.0045x; 1.0045x over previous
//
#include <hip/hip_runtime.h>
#include <cstdint>
#include <cstddef>

#define B_SZ   8
#define SEQ    4096
#define HID    1024
#define NCH    8         // snn time chunks -> 512 blocks = 2 blocks/CU (TLP covers DMA drain)
#define CHUNK  512       // SEQ / NCH
#define WARM   256       // warm-up steps; bit-exact (validated rounds 4-6)
#define JTAP   16        // truncated SSM impulse-response taps
#define TS     32        // yout t-tile
#define TT     32        // snn LDS time-tile
#define HB     128       // snn hid-slab per block

typedef float vfloat4 __attribute__((ext_vector_type(4)));

// ws layout: u64 spk[B_SZ*16*SEQ] = 4 MB at offset 0
__device__ __forceinline__ void snn_step(float& v, float& r, float xv, bool& s) {
  // match reference rounding: separate mul + add (no FMA contraction)
  v = __fadd_rn(__fmul_rn(v, 0.9f), xv);
  s = (r <= 0.0f) && (v >= 1.0f);
  v = s ? 0.0f : v;
  r = s ? 5.0f : fmaxf(r - 1.0f, 0.0f);
}

// async global->LDS DMA, 16B/lane (wave-uniform LDS base + lane*16)
__device__ __forceinline__ void async_ld16(const float* g, float* l) {
  __builtin_amdgcn_global_load_lds((const __attribute__((address_space(1))) void*)g,
                                   (__attribute__((address_space(3))) void*)l,
                                   16, 0, 0);
}

// Phase 1: LIF scan. grid = (8, B_SZ, NCH) = 512 blocks of 128 threads (2/CU).
// x streamed via async DMA into double-buffered LDS tiles (32t x 128hid); the
// per-tile barrier drain is covered by the co-resident block's compute.
__global__ __launch_bounds__(128) void snn_kernel(const float* __restrict__ x,
                                                  unsigned long long* __restrict__ spk) {
  __shared__ float tile[2][TT][HB];        // 2 x 16 KB
  const int tid  = threadIdx.x;            // 0..127
  const int lane = tid & 63;
  const int w    = tid >> 6;               // wave 0/1
  const int hb   = blockIdx.x;             // hid slab 0..7
  const int b    = blockIdx.y;
  const int c    = blockIdx.z;             // chunk 0..7
  const int t0   = c * CHUNK;
  const int tw   = (c == 0) ? 0 : (t0 - WARM);
  const int nt   = (t0 + CHUNK - tw) / TT; // 16 or 24 tiles
  const float* __restrict__ gbase = x + (size_t)(b * SEQ) * HID + hb * HB;
  const int wv = hb * 2 + w;               // global hid-wave index 0..15
  unsigned long long* __restrict__ sp = spk + (size_t)(b * 16 + wv) * SEQ;

  // per-lane offset within a 1KB (2-row) DMA segment: lanes 0-31 row+0, 32-63 row+1
  const size_t goff = (size_t)(lane >> 5) * HID + (size_t)(lane & 31) * 4;

  // prefetch tile 0
  {
    const float* g0 = gbase + (size_t)tw * HID + goff;
    float* l0 = &tile[0][0][0];
    #pragma unroll
    for (int p = 0; p < 8; ++p)
      async_ld16(g0 + (size_t)(w * 16 + 2 * p) * HID, l0 + (w * 8 + p) * 256);
  }

  float v = 0.0f, r = 0.0f;
  for (int i = 0; i < nt; ++i) {
    __syncthreads();                       // drains DMA: tile i resident
    const int tt = tw + i * TT;

    if (i + 1 < nt) {                      // prefetch tile i+1 (flies during process)
      const float* g = gbase + (size_t)(tt + TT) * HID + goff;
      float* l = &tile[(i + 1) & 1][0][0];
      #pragma unroll
      for (int p = 0; p < 8; ++p)
        async_ld16(g + (size_t)(w * 16 + 2 * p) * HID, l + (w * 8 + p) * 256);
    }

    const float (*tl)[HB] = tile[i & 1];
    if (tt >= t0) {                        // emit tile (wave-uniform branch)
      unsigned long long my = 0;
      #pragma unroll
      for (int g8 = 0; g8 < 4; ++g8) {
        float xv[8];
        #pragma unroll
        for (int k = 0; k < 8; ++k) xv[k] = tl[g8 * 8 + k][tid];
        #pragma unroll
        for (int k = 0; k < 8; ++k) {
          bool s; snn_step(v, r, xv[k], s);
          unsigned long long m = __ballot(s);
          my = ((lane & 31) == (g8 * 8 + k)) ? m : my;
        }
      }
      if (lane < 32) sp[tt + lane] = my;   // 256B coalesced burst per tile
    } else {                               // warm-up tile
      #pragma unroll
      for (int g8 = 0; g8 < 4; ++g8) {
        float xv[8];
        #pragma unroll
        for (int k = 0; k < 8; ++k) xv[k] = tl[g8 * 8 + k][tid];
        #pragma unroll
        for (int k = 0; k < 8; ++k) { bool s; snn_step(v, r, xv[k], s); }
      }
    }
  }
}

// Phase 2 (fused): grid = (SEQ/TS, B_SZ) = 1024 blocks (4/CU).
// wave0 computes w_m = C.A^m.B (overlapped with staging by waves 1-3);
// u popcounts, 16-tap conv, nontemporal stream-out.
__global__ __launch_bounds__(256) void yout_kernel(const unsigned long long* __restrict__ spk,
                                                   const float* __restrict__ A,
                                                   const float* __restrict__ Bv,
                                                   const float* __restrict__ Cv,
                                                   const float* __restrict__ Dp,
                                                   vfloat4* __restrict__ out) {
  __shared__ unsigned long long lm[16][TS + JTAP];
  __shared__ float ws[JTAP];
  __shared__ float su[TS + JTAP];
  __shared__ float sy[TS];

  const int tid = threadIdx.x;
  const int b   = blockIdx.y;
  const int t0  = blockIdx.x * TS;
  const unsigned long long* __restrict__ sb = spk + (size_t)b * 16 * SEQ;

  if (tid < 64) {
    const int lane = tid;
    float arow[64];
    #pragma unroll 8
    for (int s2 = 0; s2 < 64; ++s2) arow[s2] = A[lane * 64 + s2];
    float p = Bv[lane];
    const float cv = Cv[lane];
    for (int m = 0; m < JTAP; ++m) {
      float t = cv * p;
      #pragma unroll
      for (int off = 32; off; off >>= 1) t += __shfl_xor(t, off);
      if (lane == 0) ws[m] = t;
      float n0 = 0.f, n1 = 0.f, n2 = 0.f, n3 = 0.f;
      #pragma unroll
      for (int s2 = 0; s2 < 64; s2 += 4) {
        n0 = fmaf(arow[s2 + 0], __shfl(p, s2 + 0), n0);
        n1 = fmaf(arow[s2 + 1], __shfl(p, s2 + 1), n1);
        n2 = fmaf(arow[s2 + 2], __shfl(p, s2 + 2), n2);
        n3 = fmaf(arow[s2 + 3], __shfl(p, s2 + 3), n3);
      }
      p = (n0 + n1) + (n2 + n3);
    }
  } else {
    const int i = tid - 64;
    if (i < TS + JTAP) {
      const int t = t0 - JTAP + i;
      #pragma unroll
      for (int wv = 0; wv < 16; ++wv)
        lm[wv][i] = (t >= 0) ? sb[(size_t)wv * SEQ + t] : 0ull;
    }
  }
  __syncthreads();

  if (tid < TS + JTAP) {
    int cc = 0;
    #pragma unroll
    for (int wv = 0; wv < 16; ++wv) cc += __popcll(lm[wv][tid]);
    su[tid] = cc * (1.0f / 1024.0f);
  }
  __syncthreads();

  if (tid < TS) {
    float acc = Dp[0] * su[JTAP + tid];
    #pragma unroll
    for (int m = 0; m < JTAP; ++m) acc = fmaf(ws[m], su[JTAP + tid - m], acc);
    sy[tid] = acc;
  }
  __syncthreads();

  const int wv = tid >> 4;
  const int sh = (tid & 15) * 4;
  vfloat4* op = out + (size_t)(b * SEQ + t0) * 256 + tid;
  #pragma unroll 8
  for (int j = 0; j < TS; ++j) {
    const unsigned long long m = lm[wv][JTAP + j];
    const float yv = sy[j];
    vfloat4 o;
    o.x = ((m >> (sh + 0)) & 1ull) ? 1.0f + yv : yv;
    o.y = ((m >> (sh + 1)) & 1ull) ? 1.0f + yv : yv;
    o.z = ((m >> (sh + 2)) & 1ull) ? 1.0f + yv : yv;
    o.w = ((m >> (sh + 3)) & 1ull) ? 1.0f + yv : yv;
    __builtin_nontemporal_store(o, &op[(size_t)j * 256]);
  }
}

extern "C" void kernel_launch(void* const* d_in, const int* in_sizes, int n_in,
                              void* d_out, int out_size, void* d_ws, size_t ws_size,
                              hipStream_t stream) {
  const float* x  = (const float*)d_in[0];   // (8, 4096, 1024)
  const float* A  = (const float*)d_in[1];   // (64, 64)
  const float* Bv = (const float*)d_in[2];   // (64, 1)
  const float* Cv = (const float*)d_in[3];   // (1, 64)
  const float* Dp = (const float*)d_in[4];   // (1, 1)

  unsigned long long* spk = (unsigned long long*)d_ws;   // 4 MB

  dim3 g1(HID / HB, B_SZ, NCH);
  snn_kernel<<<g1, 128, 0, stream>>>(x, spk);

  dim3 g2(SEQ / TS, B_SZ);
  yout_kernel<<<g2, 256, 0, stream>>>(spk, A, Bv, Cv, Dp, (vfloat4*)d_out);
}